// Round 2
// baseline (241.927 us; speedup 1.0000x reference)
//
#include <hip/hip_runtime.h>
#include <hip/hip_bf16.h>

namespace {

constexpr int kN = 64, kC = 128, kT = 128, kV = 25, kH = 8, kc = 16;

typedef __attribute__((ext_vector_type(8))) short bf16x8;
typedef __attribute__((ext_vector_type(4))) float f32x4;

__device__ inline unsigned short f2bf(float f) {
    unsigned int u = __builtin_bit_cast(unsigned int, f);
    u += 0x7fffu + ((u >> 16) & 1u);   // round-to-nearest-even
    return (unsigned short)(u >> 16);
}

__device__ inline void glds16(const unsigned short* g, unsigned short* l) {
    __builtin_amdgcn_global_load_lds(
        (const __attribute__((address_space(1))) void*)g,
        (__attribute__((address_space(3))) void*)l, 16, 0, 0);
}

// ---------------- P0: x (fp32) -> xb (bf16), GEMM A-staging order ------------
// xb[n][ch][kg(4)][t(128)][j(8)], v = kg*8+j (>=25 -> 0). 4096 shorts/(n,ch).
__global__ void prep_x(const float* __restrict__ x, unsigned short* __restrict__ xb) {
    int nc = blockIdx.x;                       // n*128 + ch
    const float* xr = x + (size_t)nc * (kT * kV);
    unsigned short* ob = xb + (size_t)nc * 4096;
    int tid = threadIdx.x;
    #pragma unroll
    for (int q = 0; q < 2; ++q) {
        int u = tid + q * 256;                 // unit = kg*128 + t
        int kg = u >> 7, t = u & 127;
        const float* row = xr + t * kV + kg * 8;
        bf16x8 o;
        #pragma unroll
        for (int j = 0; j < 8; ++j) {
            int v = kg * 8 + j;
            o[j] = (short)(v < kV ? f2bf(row[j]) : (unsigned short)0);
        }
        *(bf16x8*)(ob + (size_t)u * 8) = o;
    }
}

// ---------------- P1: w1_i[h][v][w] = fc1/||.|| + pe/||.||  (norm over v) ----
__global__ void precompute_w1(const float* __restrict__ fc1,
                              const float* __restrict__ rpe,
                              const int* __restrict__ hops,
                              float* __restrict__ W1) {
    int ih = blockIdx.x;        // i*8+h, 0..23
    int w = threadIdx.x;
    if (w >= kV) return;
    const float* f = fc1 + ih * kV * kV;
    const float* r = rpe + ih * kV;
    float s1 = 0.f, s2 = 0.f;
    for (int v = 0; v < kV; ++v) {
        float a = f[v * kV + w];
        float p = r[hops[v * kV + w]];
        s1 += a * a; s2 += p * p;
    }
    float n1 = sqrtf(s1) + 1e-4f, n2 = sqrtf(s2) + 1e-4f;
    float* o = W1 + ih * kV * kV;
    for (int v = 0; v < kV; ++v) {
        float a = f[v * kV + w];
        float p = r[hops[v * kV + w]];
        o[v * kV + w] = a / n1 + p / n2;
    }
}

// ---------------- P2: combined weight, per-col-half staging layout -----------
// Wt2[h][cb(2)][c(16)][kg(4)][mh(256)][j(8)]; m = cb*208+mh (mh>=208 -> 0)
// element = sum_i wg_i[h, d=m/25, c] * w1_i[h, v=kg*8+j, w=m%25]
__global__ void precompute_W(const float* __restrict__ W1,
                             const float* __restrict__ fc2_w,
                             unsigned short* __restrict__ Wt2) {
    int c   = blockIdx.x;       // 0..15
    int hcb = blockIdx.y;       // h*2+cb, 0..15
    int h = hcb >> 1, cb = hcb & 1;
    unsigned short* outp = Wt2 + ((size_t)hcb * 16 + c) * 8192;
    for (int e = threadIdx.x; e < 8192; e += 256) {
        int kg = e >> 11;
        int rem = e & 2047;
        int mh = rem >> 3;
        int j = rem & 7;
        int v = kg * 8 + j;
        int m = cb * 208 + mh;
        float val = 0.f;
        if (mh < 208 && m < 400 && v < kV) {
            int d = m / 25, w = m - d * 25;
            #pragma unroll
            for (int i = 0; i < 3; ++i) {
                float wg = fc2_w[(i * kC + h * kc + d) * kc + c];
                float w1 = W1[((i * kH + h) * kV + v) * kV + w];
                val += wg * w1;
            }
        }
        outp[e] = f2bf(val);
    }
}

// ---------------- A: y = x * W  (per head, MFMA bf16, dbuf + glds) -----------
// block: 128 rows (= one n, all t) x 208 cols (col-half); 4 waves = 4 row-grps
__global__ __launch_bounds__(256, 3) void gemm_y(const unsigned short* __restrict__ xb,
                                                 const unsigned short* __restrict__ Wt2,
                                                 float* __restrict__ y) {
    __shared__ __align__(16) unsigned short Ald[2][4][128][8];   // 16 KB
    __shared__ __align__(16) unsigned short Bld[2][4][256][8];   // 32 KB

    const int n  = blockIdx.x;      // 0..63
    const int cb = blockIdx.y;      // 0..1
    const int h  = blockIdx.z;      // 0..7
    const int tid  = threadIdx.x;
    const int lane = tid & 63;
    const int wv = tid >> 6;        // wave = row group (32 rows)
    const int ll = lane & 15, lh = lane >> 4;

    const unsigned short* abase = xb  + (size_t)(n * kC + h * kc) * 4096;
    const unsigned short* bbase = Wt2 + ((size_t)(h * 2 + cb) * 16) * 8192;

    f32x4 acc[2][13];
    #pragma unroll
    for (int a = 0; a < 2; ++a)
        #pragma unroll
        for (int b = 0; b < 13; ++b) acc[a][b] = (f32x4)(0.f);

    auto stage = [&](int c, int buf) {
        const unsigned short* as = abase + (size_t)c * 4096;
        unsigned short* al = &Ald[buf][0][0][0];
        glds16(as + (size_t)tid * 8,         al + (size_t)tid * 8);
        glds16(as + (size_t)(tid + 256) * 8, al + (size_t)(tid + 256) * 8);
        const unsigned short* bs = bbase + (size_t)c * 8192;
        unsigned short* bl = &Bld[buf][0][0][0];
        #pragma unroll
        for (int k = 0; k < 4; ++k)
            glds16(bs + (size_t)(k * 256 + tid) * 8, bl + (size_t)(k * 256 + tid) * 8);
    };

    stage(0, 0);
    __syncthreads();

    for (int c = 0; c < 16; ++c) {
        const int cur = c & 1;
        if (c < 15) stage(c + 1, cur ^ 1);     // loads fly during compute

        bf16x8 af0 = *(const bf16x8*)&Ald[cur][lh][wv * 32 + ll][0];
        bf16x8 af1 = *(const bf16x8*)&Ald[cur][lh][wv * 32 + 16 + ll][0];
        #pragma unroll
        for (int ci = 0; ci < 13; ++ci) {
            bf16x8 bf = *(const bf16x8*)&Bld[cur][lh][ci * 16 + ll][0];
            acc[0][ci] = __builtin_amdgcn_mfma_f32_16x16x32_bf16(af0, bf, acc[0][ci], 0, 0, 0);
            acc[1][ci] = __builtin_amdgcn_mfma_f32_16x16x32_bf16(af1, bf, acc[1][ci], 0, 0, 0);
        }
        __syncthreads();   // drains vmcnt -> next buffer ready, this one reusable
    }

    // epilogue: D lane map col=lane&15, row=(lane>>4)*4+reg
    #pragma unroll
    for (int rt = 0; rt < 2; ++rt) {
        int t = wv * 32 + rt * 16 + lh * 4;
        #pragma unroll
        for (int ci = 0; ci < 13; ++ci) {
            int m = cb * 208 + ci * 16 + ll;
            if (m < 400) {
                int d = m / 25, w = m - d * 25;
                float* yp = y + ((size_t)(n * kC + h * kc + d) * kT + t) * kV + w;
                #pragma unroll
                for (int r = 0; r < 4; ++r)
                    yp[(size_t)r * kV] = acc[rt][ci][r];
            }
        }
    }
}

// ---------------- B1/B2: deterministic per-channel BN stats ------------------
__global__ void bn_partial(const float* __restrict__ y, float2* __restrict__ partials) {
    int g  = blockIdx.x;    // 0..7 (n-split)
    int ch = blockIdx.y;    // 0..127
    int tid = threadIdx.x;
    float s = 0.f, ss = 0.f;
    for (int n = g * 8; n < g * 8 + 8; ++n) {
        const float* p = y + (size_t)(n * kC + ch) * kT * kV;
        for (int e = tid; e < kT * kV; e += 256) {
            float v = p[e];
            s += v; ss += v * v;
        }
    }
    __shared__ float rs[256], rss[256];
    rs[tid] = s; rss[tid] = ss;
    __syncthreads();
    for (int o = 128; o > 0; o >>= 1) {
        if (tid < o) { rs[tid] += rs[tid + o]; rss[tid] += rss[tid + o]; }
        __syncthreads();
    }
    if (tid == 0) partials[ch * 8 + g] = make_float2(rs[0], rss[0]);
}

__global__ void bn_finalize(const float2* __restrict__ partials,
                            const float* __restrict__ gamma,
                            const float* __restrict__ beta,
                            float2* __restrict__ scsh) {
    int ch = threadIdx.x;
    if (ch >= kC) return;
    float s = 0.f, ss = 0.f;
    for (int g = 0; g < 8; ++g) {
        float2 p = partials[ch * 8 + g];
        s += p.x; ss += p.y;
    }
    const float inv = 1.f / (float)(kN * kT * kV);
    float mean = s * inv;
    float var  = ss * inv - mean * mean;
    float sc = gamma[ch] * rsqrtf(var + 1e-5f);
    scsh[ch] = make_float2(sc, beta[ch] - mean * sc);
}

// ---------------- C: out = relu(y*scale + shift + x), in place ---------------
__global__ void bn_apply(float* __restrict__ y, const float* __restrict__ x,
                         const float2* __restrict__ scsh) {
    const size_t total4 = (size_t)kN * kC * kT * kV / 4;   // 6,553,600
    for (size_t i = (size_t)blockIdx.x * blockDim.x + threadIdx.x; i < total4;
         i += (size_t)gridDim.x * blockDim.x) {
        int ch = (int)((i / 800) % kC);          // T*V/4 = 800 float4 per (n,ch)
        float2 sc = scsh[ch];
        f32x4 yv = ((const f32x4*)y)[i];
        f32x4 xv = ((const f32x4*)x)[i];
        f32x4 o;
        #pragma unroll
        for (int q = 0; q < 4; ++q)
            o[q] = fmaxf(yv[q] * sc.x + sc.y + xv[q], 0.f);
        ((f32x4*)y)[i] = o;
    }
}

} // namespace

extern "C" void kernel_launch(void* const* d_in, const int* in_sizes, int n_in,
                              void* d_out, int out_size, void* d_ws, size_t ws_size,
                              hipStream_t stream) {
    const float* x     = (const float*)d_in[0];
    const float* fc1   = (const float*)d_in[1];
    const float* rpe   = (const float*)d_in[2];
    const int*   hops  = (const int*)d_in[3];
    const float* fc2w  = (const float*)d_in[4];
    // d_in[5] = fc2_b: constant over BN reduction axes -> cancelled by BN.
    const float* gamma = (const float*)d_in[6];
    const float* beta  = (const float*)d_in[7];
    float* y = (float*)d_out;

    char* ws = (char*)d_ws;
    unsigned short* xbuf     = (unsigned short*)ws;                     // 67,108,864 B
    float*          W1       = (float*)(ws + 67108864);                 // 60,000 B
    unsigned short* Wt2      = (unsigned short*)(ws + 67174400);        // 4,194,304 B
    float2*         partials = (float2*)(ws + 71368704);                // 8,192 B
    float2*         scsh     = (float2*)(ws + 71376896);                // 1,024 B

    prep_x<<<8192, 256, 0, stream>>>(x, xbuf);
    precompute_w1<<<24, 32, 0, stream>>>(fc1, rpe, hops, W1);
    precompute_W<<<dim3(16, 16), 256, 0, stream>>>(W1, fc2w, Wt2);
    gemm_y<<<dim3(64, 2, 8), 256, 0, stream>>>(xbuf, Wt2, y);
    bn_partial<<<dim3(8, 128), 256, 0, stream>>>(y, partials);
    bn_finalize<<<1, 128, 0, stream>>>(partials, gamma, beta, scsh);
    bn_apply<<<2048, 256, 0, stream>>>(y, x, scsh);
}

// Round 3
// 132.186 us; speedup vs baseline: 1.8302x; 1.8302x over previous
//
#include <hip/hip_runtime.h>
#include <hip/hip_bf16.h>

namespace {

constexpr int kN = 64, kC = 128, kT = 128, kV = 25, kH = 8, kc = 16;

typedef __attribute__((ext_vector_type(8))) short bf16x8;
typedef __attribute__((ext_vector_type(8))) unsigned short u16x8;
typedef __attribute__((ext_vector_type(4))) float f32x4;

__device__ inline unsigned short f2bf(float f) {
    unsigned int u = __builtin_bit_cast(unsigned int, f);
    u += 0x7fffu + ((u >> 16) & 1u);   // round-to-nearest-even
    return (unsigned short)(u >> 16);
}

__device__ inline float bf2f(unsigned short s) {
    return __builtin_bit_cast(float, ((unsigned int)s) << 16);
}

__device__ inline void glds16(const void* g, void* l) {
    __builtin_amdgcn_global_load_lds(
        (const __attribute__((address_space(1))) void*)g,
        (__attribute__((address_space(3))) void*)l, 16, 0, 0);
}

// ---------------- P1: w1_i[h][v][w] = fc1/||.|| + pe/||.||  (norm over v) ----
__global__ void precompute_w1(const float* __restrict__ fc1,
                              const float* __restrict__ rpe,
                              const int* __restrict__ hops,
                              float* __restrict__ W1) {
    int ih = blockIdx.x;        // i*8+h, 0..23
    int w = threadIdx.x;
    if (w >= kV) return;
    const float* f = fc1 + ih * kV * kV;
    const float* r = rpe + ih * kV;
    float s1 = 0.f, s2 = 0.f;
    for (int v = 0; v < kV; ++v) {
        float a = f[v * kV + w];
        float p = r[hops[v * kV + w]];
        s1 += a * a; s2 += p * p;
    }
    float n1 = sqrtf(s1) + 1e-4f, n2 = sqrtf(s2) + 1e-4f;
    float* o = W1 + ih * kV * kV;
    for (int v = 0; v < kV; ++v) {
        float a = f[v * kV + w];
        float p = r[hops[v * kV + w]];
        o[v * kV + w] = a / n1 + p / n2;
    }
}

// ---------------- P2: combined weight, per-col-half staging layout -----------
// Wt2[h][cb(2)][c(16)][kg(4)][mh(256)][j(8)]; m = cb*208+mh (mh>=208 -> 0)
// element = sum_i wg_i[h, d=m/25, c] * w1_i[h, v=kg*8+j, w=m%25]
__global__ void precompute_W(const float* __restrict__ W1,
                             const float* __restrict__ fc2_w,
                             unsigned short* __restrict__ Wt2) {
    int c   = blockIdx.x;       // 0..15
    int hcb = blockIdx.y;       // h*2+cb, 0..15
    int h = hcb >> 1, cb = hcb & 1;
    unsigned short* outp = Wt2 + ((size_t)hcb * 16 + c) * 8192;
    for (int e = threadIdx.x; e < 8192; e += 256) {
        int kg = e >> 11;
        int rem = e & 2047;
        int mh = rem >> 3;
        int j = rem & 7;
        int v = kg * 8 + j;
        int m = cb * 208 + mh;
        float val = 0.f;
        if (mh < 208 && m < 400 && v < kV) {
            int d = m / 25, w = m - d * 25;
            #pragma unroll
            for (int i = 0; i < 3; ++i) {
                float wg = fc2_w[(i * kC + h * kc + d) * kc + c];
                float w1 = W1[((i * kH + h) * kV + v) * kV + w];
                val += wg * w1;
            }
        }
        outp[e] = f2bf(val);
    }
}

// ---------------- A: y = x * W  (fused fp32->bf16, MFMA, bf16 out) -----------
// block: 64 rows (t-half of one n) x 208 cols (cb-half); 4 waves = 2 rg x 2 cg
// A-path: glds x fp32 slab -> LDS bounce -> reg fragments (convert in reg)
__global__ __launch_bounds__(256, 4) void gemm_y(const float* __restrict__ x,
                                                 const unsigned short* __restrict__ Wt2,
                                                 unsigned short* __restrict__ yb) {
    __shared__ __align__(16) float bounce[1632];                 // 64*25 + pad
    __shared__ __align__(16) unsigned short Bld[2][4][256][8];   // 32 KB

    const int n  = blockIdx.x;          // 0..63
    const int yq = blockIdx.y;          // tb*2+cb, 0..3
    const int h  = blockIdx.z;          // 0..7
    const int tb = yq >> 1, cb = yq & 1, tbase = tb * 64;
    const int tid = threadIdx.x, lane = tid & 63;
    const int wv = tid >> 6, rg = wv >> 1, cg = wv & 1;
    const int ll = lane & 15, lh = lane >> 4;

    const float* abase = x + ((size_t)(n * kC + h * kc) * kT + tbase) * kV;
    const unsigned short* bbase = Wt2 + ((size_t)(h * 2 + cb) * 16) * 8192;

    f32x4 acc[2][7];
    #pragma unroll
    for (int a = 0; a < 2; ++a)
        #pragma unroll
        for (int b = 0; b < 7; ++b) acc[a][b] = (f32x4)(0.f);
    bf16x8 af0 = {}, af1 = {};

    auto stage_b = [&](int c, int buf) {
        const unsigned short* bs = bbase + (size_t)c * 8192;
        unsigned short* bl = &Bld[buf][0][0][0];
        #pragma unroll
        for (int k = 0; k < 4; ++k)
            glds16(bs + (size_t)(k * 256 + tid) * 8, bl + (size_t)(k * 256 + tid) * 8);
    };
    auto stage_x = [&](int c) {   // 400 float4 = 64 rows x 25 v, contiguous
        const float* as = abase + (size_t)c * (kT * kV);
        glds16(as + (size_t)tid * 4, &bounce[tid * 4]);
        if (tid < 144) glds16(as + (size_t)(256 + tid) * 4, &bounce[(256 + tid) * 4]);
    };
    auto convert = [&]() {        // build A fragments in registers
        const float* bp = &bounce[(rg * 32 + ll) * kV + lh * 8];
        #pragma unroll
        for (int j = 0; j < 8; ++j) {
            unsigned short s0 = f2bf(bp[j]);
            unsigned short s1 = f2bf(bp[j + 16 * kV]);
            bool ok = (lh * 8 + j) < kV;
            af0[j] = ok ? (short)s0 : (short)0;
            af1[j] = ok ? (short)s1 : (short)0;
        }
    };

    stage_x(0); stage_b(0, 0);
    __syncthreads();              // vmcnt(0): bounce + Bld[0] ready
    convert();
    __syncthreads();              // bounce free for stage_x(1)

    for (int c = 0; c < 16; ++c) {
        const int cur = c & 1;
        if (c < 15) { stage_b(c + 1, cur ^ 1); stage_x(c + 1); }

        #pragma unroll
        for (int ci = 0; ci < 7; ++ci) {
            if (cg == 0 || ci < 6) {
                bf16x8 bf = *(const bf16x8*)&Bld[cur][lh][(cg * 7 + ci) * 16 + ll][0];
                acc[0][ci] = __builtin_amdgcn_mfma_f32_16x16x32_bf16(af0, bf, acc[0][ci], 0, 0, 0);
                acc[1][ci] = __builtin_amdgcn_mfma_f32_16x16x32_bf16(af1, bf, acc[1][ci], 0, 0, 0);
            }
        }
        __syncthreads();          // drains stage glds; Bld[cur]/bounce reads done
        if (c < 15) {
            convert();            // fragments for c+1 from fresh bounce
            __syncthreads();      // bounce free for next stage_x
        }
    }

    // epilogue: D map col=lane&15, row=(lane>>4)*4+reg; store bf16
    #pragma unroll
    for (int rt = 0; rt < 2; ++rt) {
        int t = tbase + rg * 32 + rt * 16 + lh * 4;
        #pragma unroll
        for (int ci = 0; ci < 7; ++ci) {
            if (cg == 1 && ci == 6) continue;     // tile 13 = other cb-half
            int m = cb * 208 + (cg * 7 + ci) * 16 + ll;
            if (m < 400) {
                int d = m / 25, w = m - d * 25;
                unsigned short* yp = yb + ((size_t)(n * kC + h * kc + d) * kT + t) * kV + w;
                #pragma unroll
                for (int r = 0; r < 4; ++r)
                    yp[(size_t)r * kV] = f2bf(acc[rt][ci][r]);
            }
        }
    }
}

// ---------------- B1/B2: deterministic per-channel BN stats (bf16 y) ---------
__global__ void bn_partial(const unsigned short* __restrict__ yb,
                           float2* __restrict__ partials) {
    int g  = blockIdx.x;    // 0..7 (n-split)
    int ch = blockIdx.y;    // 0..127
    int tid = threadIdx.x;
    float s = 0.f, ss = 0.f;
    for (int n = g * 8; n < g * 8 + 8; ++n) {
        const u16x8* p = (const u16x8*)(yb + (size_t)(n * kC + ch) * (kT * kV));
        for (int e = tid; e < 400; e += 256) {
            u16x8 v = p[e];
            #pragma unroll
            for (int j = 0; j < 8; ++j) {
                float f = bf2f((unsigned short)v[j]);
                s += f; ss += f * f;
            }
        }
    }
    __shared__ float rs[256], rss[256];
    rs[tid] = s; rss[tid] = ss;
    __syncthreads();
    for (int o = 128; o > 0; o >>= 1) {
        if (tid < o) { rs[tid] += rs[tid + o]; rss[tid] += rss[tid + o]; }
        __syncthreads();
    }
    if (tid == 0) partials[ch * 8 + g] = make_float2(rs[0], rss[0]);
}

__global__ void bn_finalize(const float2* __restrict__ partials,
                            const float* __restrict__ gamma,
                            const float* __restrict__ beta,
                            float2* __restrict__ scsh) {
    int ch = threadIdx.x;
    if (ch >= kC) return;
    float s = 0.f, ss = 0.f;
    for (int g = 0; g < 8; ++g) {
        float2 p = partials[ch * 8 + g];
        s += p.x; ss += p.y;
    }
    const float inv = 1.f / (float)(kN * kT * kV);
    float mean = s * inv;
    float var  = ss * inv - mean * mean;
    float sc = gamma[ch] * rsqrtf(var + 1e-5f);
    scsh[ch] = make_float2(sc, beta[ch] - mean * sc);
}

// ---------------- C: out = relu(y*scale + shift + x) -------------------------
__global__ void bn_apply(const unsigned short* __restrict__ yb,
                         const float* __restrict__ x,
                         const float2* __restrict__ scsh,
                         float* __restrict__ out) {
    const size_t total8 = (size_t)kN * kC * kT * kV / 8;   // 3,276,800
    for (size_t i = (size_t)blockIdx.x * blockDim.x + threadIdx.x; i < total8;
         i += (size_t)gridDim.x * blockDim.x) {
        int ch = (int)((i / 400) % kC);          // 400 u16x8 per (n,ch)
        float2 sc = scsh[ch];
        u16x8 yv = ((const u16x8*)yb)[i];
        f32x4 x0 = ((const f32x4*)x)[i * 2];
        f32x4 x1 = ((const f32x4*)x)[i * 2 + 1];
        f32x4 o0, o1;
        #pragma unroll
        for (int q = 0; q < 4; ++q) {
            o0[q] = fmaxf(bf2f((unsigned short)yv[q]) * sc.x + sc.y + x0[q], 0.f);
            o1[q] = fmaxf(bf2f((unsigned short)yv[q + 4]) * sc.x + sc.y + x1[q], 0.f);
        }
        ((f32x4*)out)[i * 2]     = o0;
        ((f32x4*)out)[i * 2 + 1] = o1;
    }
}

} // namespace

extern "C" void kernel_launch(void* const* d_in, const int* in_sizes, int n_in,
                              void* d_out, int out_size, void* d_ws, size_t ws_size,
                              hipStream_t stream) {
    const float* x     = (const float*)d_in[0];
    const float* fc1   = (const float*)d_in[1];
    const float* rpe   = (const float*)d_in[2];
    const int*   hops  = (const int*)d_in[3];
    const float* fc2w  = (const float*)d_in[4];
    // d_in[5] = fc2_b: constant over BN reduction axes -> cancelled by BN.
    const float* gamma = (const float*)d_in[6];
    const float* beta  = (const float*)d_in[7];
    float* out = (float*)d_out;

    char* ws = (char*)d_ws;
    unsigned short* yb       = (unsigned short*)ws;                  // 52,428,800 B
    float*          W1       = (float*)(ws + 52428800);              // 60,000 B
    unsigned short* Wt2      = (unsigned short*)(ws + 52494336);     // 4,194,304 B
    float2*         partials = (float2*)(ws + 56688640);             // 8,192 B
    float2*         scsh     = (float2*)(ws + 56696832);             // 1,024 B

    precompute_w1<<<24, 32, 0, stream>>>(fc1, rpe, hops, W1);
    precompute_W<<<dim3(16, 16), 256, 0, stream>>>(W1, fc2w, Wt2);
    gemm_y<<<dim3(64, 4, 8), 256, 0, stream>>>(x, Wt2, yb);
    bn_partial<<<dim3(8, 128), 256, 0, stream>>>(yb, partials);
    bn_finalize<<<1, 128, 0, stream>>>(partials, gamma, beta, scsh);
    bn_apply<<<2048, 256, 0, stream>>>(yb, x, scsh, out);
}